// Round 1
// baseline (11466.184 us; speedup 1.0000x reference)
//
#include <hip/hip_runtime.h>

// ---------------------------------------------------------------------------
// 2-layer GRU (B=64, T=1024, D=256, H=512) + dense head, persistent-RNN style.
// One persistent kernel runs both layers' scans pipelined (layer1 trails by 1
// step), with W_h fragments LDS-resident, W_i fragments register-resident,
// fp16 MFMA (fp32 accum), fp32 carried state in registers, and a device-scope
// grid barrier per step (1024 barriers total).
// ---------------------------------------------------------------------------

#define T_STEPS 1024
#define NWG_L0  32
#define NWG_L1  32
#define NWG_TOT 64

typedef _Float16 f16x8 __attribute__((ext_vector_type(8)));
typedef float    f32x4 __attribute__((ext_vector_type(4)));

// ws layout (bytes):
//   0      h0[2][64][512] f16   (131072)
//   131072 h1[2][64][512] f16   (131072)
//   262144 y0[2][64][512] f16   (131072)
//   393216 barrier {cnt, flag}
#define H0_OFF  0
#define H1_OFF  131072
#define Y0_OFF  262144
#define BAR_OFF 393216

__device__ __forceinline__ float sigm_f(float x)  { return 1.0f / (1.0f + __expf(-x)); }
__device__ __forceinline__ float tanh_f(float x)  { return 2.0f / (1.0f + __expf(-2.0f * x)) - 1.0f; }

__device__ __forceinline__ f32x4 mfma16(f16x8 a, f16x8 b, f32x4 c) {
    return __builtin_amdgcn_mfma_f32_16x16x32_f16(a, b, c, 0, 0, 0);
}

// pack 8 strided fp32 into an f16x8 fragment
__device__ __forceinline__ f16x8 pack8(const float* __restrict__ src, int stride) {
    f16x8 r;
#pragma unroll
    for (int j = 0; j < 8; ++j) r[j] = (_Float16)src[j * stride];
    return r;
}

// grid barrier: monotonic-epoch, agent-scope release sequence.
// L1 is write-through on CDNA; __syncthreads drains vmcnt, tid0's fence +
// ACQ_REL RMW publishes the wg's stores; acquire load invalidates L1/L2.
__device__ __forceinline__ void gridbar(unsigned* cnt, unsigned* flag, unsigned epoch, int tid) {
    __syncthreads();
    if (tid == 0) {
        __threadfence();
        unsigned prev = __hip_atomic_fetch_add(cnt, 1u, __ATOMIC_ACQ_REL, __HIP_MEMORY_SCOPE_AGENT);
        if (prev == NWG_TOT - 1) {
            __hip_atomic_store(cnt, 0u, __ATOMIC_RELAXED, __HIP_MEMORY_SCOPE_AGENT);
            __hip_atomic_store(flag, epoch, __ATOMIC_RELEASE, __HIP_MEMORY_SCOPE_AGENT);
        } else {
            while (__hip_atomic_load(flag, __ATOMIC_RELAXED, __HIP_MEMORY_SCOPE_AGENT) < epoch)
                __builtin_amdgcn_s_sleep(2);
            (void)__hip_atomic_load(flag, __ATOMIC_ACQUIRE, __HIP_MEMORY_SCOPE_AGENT);
        }
    }
    __syncthreads();
}

__global__ __launch_bounds__(256, 1) void gru_scan(
    const float* __restrict__ x,     // [64,1024,256]
    const float* __restrict__ Wi0,   // [256,1536]
    const float* __restrict__ bi0,   // [1536]
    const float* __restrict__ Wh0,   // [512,1536]
    const float* __restrict__ bhn0,  // [512]
    const float* __restrict__ Wi1,   // [512,1536]
    const float* __restrict__ bi1,   // [1536]
    const float* __restrict__ Wh1,   // [512,1536]
    const float* __restrict__ bhn1,  // [512]
    float* __restrict__ c0_out,      // [64,512]
    float* __restrict__ c1_out,      // [64,512]
    unsigned char* __restrict__ ws)
{
    // W_h fragments for this wg's 48 columns (3 gates x 16 units), all 16 K-tiles
    __shared__ uint4 ldsB[48 * 64];  // 48 KB

    const int tid  = threadIdx.x;
    const int wave = tid >> 6;
    const int lane = tid & 63;
    const int quad = lane >> 4;
    const int l16  = lane & 15;
    const int wg   = blockIdx.x;
    const bool isL1 = (wg >= NWG_L0);
    const int cslice = (isL1 ? (wg - NWG_L0) : wg) * 16;

    _Float16* h0buf = (_Float16*)(ws + H0_OFF);
    _Float16* h1buf = (_Float16*)(ws + H1_OFF);
    _Float16* y0buf = (_Float16*)(ws + Y0_OFF);
    unsigned* bar_cnt  = (unsigned*)(ws + BAR_OFF);
    unsigned* bar_flag = bar_cnt + 1;

    const float* Wh = isL1 ? Wh1 : Wh0;
    const float* Wi = isL1 ? Wi1 : Wi0;

    // ---- stage W_h fragments into LDS (frag index nt*16 + kt) ----
    // B-frag layout (16x16x32): lane holds B[k = kt*32 + quad*8 + j][n = l16]
    for (int f = wave * 12; f < wave * 12 + 12; ++f) {
        int nt = f >> 4, kt = f & 15;
        const float* src = Wh + (kt * 32 + quad * 8) * 1536 + nt * 512 + cslice + l16;
        ldsB[f * 64 + lane] = __builtin_bit_cast(uint4, pack8(src, 1536));
    }

    // ---- W_i fragments in registers (every wave holds its own copy) ----
    f16x8 wif[48];
    if (!isL1) {
#pragma unroll
        for (int nt = 0; nt < 3; ++nt)
#pragma unroll
            for (int kt = 0; kt < 8; ++kt)
                wif[nt * 8 + kt] = pack8(Wi + (kt * 32 + quad * 8) * 1536 + nt * 512 + cslice + l16, 1536);
    } else {
#pragma unroll
        for (int nt = 0; nt < 3; ++nt)
#pragma unroll
            for (int kt = 0; kt < 16; ++kt)
                wif[nt * 16 + kt] = pack8(Wi + (kt * 32 + quad * 8) * 1536 + nt * 512 + cslice + l16, 1536);
    }

    // per-lane biases (fixed column cslice + l16)
    const float* bi = isL1 ? bi1 : bi0;
    const float* bh = isL1 ? bhn1 : bhn0;
    const float bi_r = bi[cslice + l16];
    const float bi_z = bi[512 + cslice + l16];
    const float bi_n = bi[1024 + cslice + l16];
    const float bhn  = bh[cslice + l16];

    __syncthreads();

    float hstate[4] = {0.f, 0.f, 0.f, 0.f};  // fp32 carried state (C-layout)
    const int rowA = wave * 16 + l16;        // A-frag batch row
    const int rowC = wave * 16 + quad * 4;   // C-frag batch row base

    for (int s = 0; s < T_STEPS + 1; ++s) {
        const int pr = s & 1;

        if (!isL1 && s < T_STEPS) {
            const int t = s;
            const _Float16* hR = h0buf + pr * 32768;
            _Float16* hW = h0buf + (pr ^ 1) * 32768;
            _Float16* yW = y0buf + (pr ^ 1) * 32768;

            f32x4 ah0 = {0,0,0,0}, ah1 = {0,0,0,0}, ah2 = {0,0,0,0};
            f32x4 ax0 = {0,0,0,0}, ax1 = {0,0,0,0}, ax2 = {0,0,0,0};

            // hidden-side: hg = h @ W_h (K = 512)
#pragma unroll
            for (int kt = 0; kt < 16; ++kt) {
                f16x8 a = *(const f16x8*)(hR + rowA * 512 + kt * 32 + quad * 8);
                ah0 = mfma16(a, __builtin_bit_cast(f16x8, ldsB[(0 * 16 + kt) * 64 + lane]), ah0);
                ah1 = mfma16(a, __builtin_bit_cast(f16x8, ldsB[(1 * 16 + kt) * 64 + lane]), ah1);
                ah2 = mfma16(a, __builtin_bit_cast(f16x8, ldsB[(2 * 16 + kt) * 64 + lane]), ah2);
            }
            // input-side: xg = x_t @ W_i0 (K = 256), fp32 -> f16 on load
#pragma unroll
            for (int kt = 0; kt < 8; ++kt) {
                const float* px = x + (size_t)rowA * 262144 + t * 256 + kt * 32 + quad * 8;
                f32x4 x0 = *(const f32x4*)(px);
                f32x4 x1 = *(const f32x4*)(px + 4);
                f16x8 a;
                a[0] = (_Float16)x0[0]; a[1] = (_Float16)x0[1]; a[2] = (_Float16)x0[2]; a[3] = (_Float16)x0[3];
                a[4] = (_Float16)x1[0]; a[5] = (_Float16)x1[1]; a[6] = (_Float16)x1[2]; a[7] = (_Float16)x1[3];
                ax0 = mfma16(a, wif[0 * 8 + kt], ax0);
                ax1 = mfma16(a, wif[1 * 8 + kt], ax1);
                ax2 = mfma16(a, wif[2 * 8 + kt], ax2);
            }
            // gates + state update (C layout: row = rowC + i, col = cslice + l16)
#pragma unroll
            for (int i = 0; i < 4; ++i) {
                const int b  = rowC + i;
                const int cu = cslice + l16;
                float r = sigm_f(ax0[i] + bi_r + ah0[i]);
                float z = sigm_f(ax1[i] + bi_z + ah1[i]);
                float n = tanh_f(ax2[i] + bi_n + r * (ah2[i] + bhn));
                float hnew = (1.0f - z) * n + z * hstate[i];
                hstate[i] = hnew;
                hW[b * 512 + cu] = (_Float16)hnew;
                yW[b * 512 + cu] = (_Float16)tanh_f(hnew);
                if (s == T_STEPS - 1) c0_out[b * 512 + cu] = hnew;
            }
        }

        if (isL1 && s >= 1) {
            const _Float16* hR = h1buf + pr * 32768;
            _Float16* hW = h1buf + (pr ^ 1) * 32768;
            const _Float16* yR = y0buf + pr * 32768;  // y0 produced at global step s-1

            f32x4 ah0 = {0,0,0,0}, ah1 = {0,0,0,0}, ah2 = {0,0,0,0};
            f32x4 ax0 = {0,0,0,0}, ax1 = {0,0,0,0}, ax2 = {0,0,0,0};

#pragma unroll
            for (int kt = 0; kt < 16; ++kt) {
                f16x8 ah = *(const f16x8*)(hR + rowA * 512 + kt * 32 + quad * 8);
                f16x8 ay = *(const f16x8*)(yR + rowA * 512 + kt * 32 + quad * 8);
                ah0 = mfma16(ah, __builtin_bit_cast(f16x8, ldsB[(0 * 16 + kt) * 64 + lane]), ah0);
                ah1 = mfma16(ah, __builtin_bit_cast(f16x8, ldsB[(1 * 16 + kt) * 64 + lane]), ah1);
                ah2 = mfma16(ah, __builtin_bit_cast(f16x8, ldsB[(2 * 16 + kt) * 64 + lane]), ah2);
                ax0 = mfma16(ay, wif[0 * 16 + kt], ax0);
                ax1 = mfma16(ay, wif[1 * 16 + kt], ax1);
                ax2 = mfma16(ay, wif[2 * 16 + kt], ax2);
            }
#pragma unroll
            for (int i = 0; i < 4; ++i) {
                const int b  = rowC + i;
                const int cu = cslice + l16;
                float r = sigm_f(ax0[i] + bi_r + ah0[i]);
                float z = sigm_f(ax1[i] + bi_z + ah1[i]);
                float n = tanh_f(ax2[i] + bi_n + r * (ah2[i] + bhn));
                float hnew = (1.0f - z) * n + z * hstate[i];
                hstate[i] = hnew;
                hW[b * 512 + cu] = (_Float16)hnew;
                if (s == T_STEPS) c1_out[b * 512 + cu] = hnew;
            }
        }

        if (s < T_STEPS) gridbar(bar_cnt, bar_flag, (unsigned)(s + 1), tid);
    }
}

// out = tanh(tanh(c1) @ W_out + b_out) : [64,512] @ [512,512], fp32
__global__ __launch_bounds__(256) void dense_out(
    const float* __restrict__ c1, const float* __restrict__ Wout,
    const float* __restrict__ bout, float* __restrict__ out)
{
    __shared__ float a[512];
    const int b = blockIdx.x, tid = threadIdx.x;
    a[tid]       = tanh_f(c1[b * 512 + tid]);
    a[tid + 256] = tanh_f(c1[b * 512 + tid + 256]);
    __syncthreads();
    float acc0 = 0.f, acc1 = 0.f;
#pragma unroll 4
    for (int k = 0; k < 512; ++k) {
        const float av = a[k];
        acc0 += av * Wout[k * 512 + tid];
        acc1 += av * Wout[k * 512 + tid + 256];
    }
    out[b * 512 + tid]       = tanh_f(acc0 + bout[tid]);
    out[b * 512 + tid + 256] = tanh_f(acc1 + bout[tid + 256]);
}

extern "C" void kernel_launch(void* const* d_in, const int* in_sizes, int n_in,
                              void* d_out, int out_size, void* d_ws, size_t ws_size,
                              hipStream_t stream)
{
    const float* x    = (const float*)d_in[0];
    const float* Wi0  = (const float*)d_in[1];
    const float* bi0  = (const float*)d_in[2];
    const float* Wh0  = (const float*)d_in[3];
    const float* bhn0 = (const float*)d_in[4];
    const float* Wi1  = (const float*)d_in[5];
    const float* bi1  = (const float*)d_in[6];
    const float* Wh1  = (const float*)d_in[7];
    const float* bhn1 = (const float*)d_in[8];
    const float* Wout = (const float*)d_in[9];
    const float* bout = (const float*)d_in[10];
    float* out = (float*)d_out;
    unsigned char* ws = (unsigned char*)d_ws;

    // zero h/y double buffers + barrier state (ws is poisoned 0xAA each launch)
    hipMemsetAsync(ws, 0, BAR_OFF + 256, stream);

    gru_scan<<<NWG_TOT, 256, 0, stream>>>(x, Wi0, bi0, Wh0, bhn0,
                                          Wi1, bi1, Wh1, bhn1,
                                          out + 32768, out + 65536, ws);
    dense_out<<<64, 256, 0, stream>>>(out + 65536, Wout, bout, out);
}

// Round 2
// 10237.685 us; speedup vs baseline: 1.1200x; 1.1200x over previous
//
#include <hip/hip_runtime.h>

// ---------------------------------------------------------------------------
// 2-layer GRU (B=64, T=1024, D=256, H=512) + dense head, persistent-RNN style.
// One persistent kernel runs both layers' scans pipelined (layer1 trails by 1
// step), W_h in LDS, W_i in registers, fp16 MFMA (fp32 accum), fp32 carried
// state, and a FLAG-ARRAY grid barrier per step (no atomic RMW contention):
// each wg release-stores its epoch to its own cache line; wave0 of every wg
// polls all 64 flags with one per-lane load + __all().
// ---------------------------------------------------------------------------

#define T_STEPS 1024
#define NWG_L0  32
#define NWG_L1  32
#define NWG_TOT 64

typedef _Float16 f16x8 __attribute__((ext_vector_type(8)));
typedef float    f32x4 __attribute__((ext_vector_type(4)));

// ws layout (bytes):
//   0      h0[2][64][512] f16   (131072)
//   131072 h1[2][64][512] f16   (131072)
//   262144 y0[2][64][512] f16   (131072)
//   393216 flags[64] (128B stride)  (8192)
#define H0_OFF   0
#define H1_OFF   131072
#define Y0_OFF   262144
#define FLAG_OFF 393216
#define FLAG_STRIDE 32   // uints = 128 B

__device__ __forceinline__ float sigm_f(float x)  { return 1.0f / (1.0f + __expf(-x)); }
__device__ __forceinline__ float tanh_f(float x)  { return 2.0f / (1.0f + __expf(-2.0f * x)) - 1.0f; }

__device__ __forceinline__ f32x4 mfma16(f16x8 a, f16x8 b, f32x4 c) {
    return __builtin_amdgcn_mfma_f32_16x16x32_f16(a, b, c, 0, 0, 0);
}

__device__ __forceinline__ f16x8 pack8(const float* __restrict__ src, int stride) {
    f16x8 r;
#pragma unroll
    for (int j = 0; j < 8; ++j) r[j] = (_Float16)src[j * stride];
    return r;
}

// ---- flag-array barrier ----
// arrive: publish this wg's stores, then store epoch to own flag line.
__device__ __forceinline__ void bar_arrive(unsigned* flags, int wg, unsigned epoch) {
    __syncthreads();                       // all waves' stores issued & vm-drained
    if (threadIdx.x == 0) {
        __builtin_amdgcn_fence(__ATOMIC_RELEASE, "agent");
        __hip_atomic_store(&flags[wg * FLAG_STRIDE], epoch,
                           __ATOMIC_RELAXED, __HIP_MEMORY_SCOPE_AGENT);
    }
}
// wait: wave0 polls all 64 flags (lane i -> flag i), then acquire.
__device__ __forceinline__ void bar_wait(const unsigned* flags, unsigned epoch,
                                         int wave, int lane) {
    if (wave == 0) {
        const unsigned* p = &flags[lane * FLAG_STRIDE];
        for (;;) {
            unsigned v = __hip_atomic_load(p, __ATOMIC_RELAXED, __HIP_MEMORY_SCOPE_AGENT);
            if (__all(v >= epoch)) break;
        }
    }
    __syncthreads();
    __builtin_amdgcn_fence(__ATOMIC_ACQUIRE, "agent");
}

__global__ __launch_bounds__(256, 1) void gru_scan(
    const float* __restrict__ x,     // [64,1024,256]
    const float* __restrict__ Wi0,   // [256,1536]
    const float* __restrict__ bi0,   // [1536]
    const float* __restrict__ Wh0,   // [512,1536]
    const float* __restrict__ bhn0,  // [512]
    const float* __restrict__ Wi1,   // [512,1536]
    const float* __restrict__ bi1,   // [1536]
    const float* __restrict__ Wh1,   // [512,1536]
    const float* __restrict__ bhn1,  // [512]
    float* __restrict__ c0_out,      // [64,512]
    float* __restrict__ c1_out,      // [64,512]
    unsigned char* __restrict__ ws)
{
    __shared__ uint4 ldsB[48 * 64];  // 48 KB: W_h fragments, frag idx nt*16+kt

    const int tid  = threadIdx.x;
    const int wave = tid >> 6;
    const int lane = tid & 63;
    const int quad = lane >> 4;
    const int l16  = lane & 15;
    const int wg   = blockIdx.x;
    const bool isL1 = (wg >= NWG_L0);
    const int cslice = (isL1 ? (wg - NWG_L0) : wg) * 16;

    _Float16* h0buf = (_Float16*)(ws + H0_OFF);
    _Float16* h1buf = (_Float16*)(ws + H1_OFF);
    _Float16* y0buf = (_Float16*)(ws + Y0_OFF);
    unsigned* flags = (unsigned*)(ws + FLAG_OFF);

    const float* Wh = isL1 ? Wh1 : Wh0;
    const float* Wi = isL1 ? Wi1 : Wi0;

    // ---- stage W_h fragments into LDS ----
    // B-frag (16x16x32): lane holds B[k = kt*32 + quad*8 + j][n = l16]
    for (int f = wave * 12; f < wave * 12 + 12; ++f) {
        int nt = f >> 4, kt = f & 15;
        const float* src = Wh + (kt * 32 + quad * 8) * 1536 + nt * 512 + cslice + l16;
        ldsB[f * 64 + lane] = __builtin_bit_cast(uint4, pack8(src, 1536));
    }

    // ---- W_i fragments in registers ----
    f16x8 wif[48];
    if (!isL1) {
#pragma unroll
        for (int nt = 0; nt < 3; ++nt)
#pragma unroll
            for (int kt = 0; kt < 8; ++kt)
                wif[nt * 8 + kt] = pack8(Wi + (kt * 32 + quad * 8) * 1536 + nt * 512 + cslice + l16, 1536);
    } else {
#pragma unroll
        for (int nt = 0; nt < 3; ++nt)
#pragma unroll
            for (int kt = 0; kt < 16; ++kt)
                wif[nt * 16 + kt] = pack8(Wi + (kt * 32 + quad * 8) * 1536 + nt * 512 + cslice + l16, 1536);
    }

    const float* bi = isL1 ? bi1 : bi0;
    const float* bh = isL1 ? bhn1 : bhn0;
    const float bi_r = bi[cslice + l16];
    const float bi_z = bi[512 + cslice + l16];
    const float bi_n = bi[1024 + cslice + l16];
    const float bhn  = bh[cslice + l16];

    __syncthreads();

    float hstate[4] = {0.f, 0.f, 0.f, 0.f};
    const int rowA = wave * 16 + l16;
    const int rowC = wave * 16 + quad * 4;

    for (int s = 0; s < T_STEPS + 1; ++s) {
        const int pr = s & 1;

        // --- prefetch x for this step (barrier-independent) ---
        f32x4 xr[16];
        if (!isL1 && s < T_STEPS) {
            const float* px = x + (size_t)rowA * 262144 + s * 256 + quad * 8;
#pragma unroll
            for (int kt = 0; kt < 8; ++kt) {
                xr[kt * 2]     = *(const f32x4*)(px + kt * 32);
                xr[kt * 2 + 1] = *(const f32x4*)(px + kt * 32 + 4);
            }
        }

        // --- wait for previous iteration's writes to be visible ---
        if (s > 0) bar_wait(flags, (unsigned)s, wave, lane);

        if (!isL1 && s < T_STEPS) {
            const _Float16* hR = h0buf + pr * 32768;
            _Float16* hW = h0buf + (pr ^ 1) * 32768;
            _Float16* yW = y0buf + (pr ^ 1) * 32768;

            f32x4 ah0 = {0,0,0,0}, ah1 = {0,0,0,0}, ah2 = {0,0,0,0};
            f32x4 ax0 = {0,0,0,0}, ax1 = {0,0,0,0}, ax2 = {0,0,0,0};

            // input-side: xg = x_t @ W_i0 (K = 256), from prefetched regs
#pragma unroll
            for (int kt = 0; kt < 8; ++kt) {
                f32x4 x0 = xr[kt * 2], x1 = xr[kt * 2 + 1];
                f16x8 a;
                a[0] = (_Float16)x0[0]; a[1] = (_Float16)x0[1]; a[2] = (_Float16)x0[2]; a[3] = (_Float16)x0[3];
                a[4] = (_Float16)x1[0]; a[5] = (_Float16)x1[1]; a[6] = (_Float16)x1[2]; a[7] = (_Float16)x1[3];
                ax0 = mfma16(a, wif[0 * 8 + kt], ax0);
                ax1 = mfma16(a, wif[1 * 8 + kt], ax1);
                ax2 = mfma16(a, wif[2 * 8 + kt], ax2);
            }
            // hidden-side: hg = h @ W_h (K = 512)
#pragma unroll
            for (int kt = 0; kt < 16; ++kt) {
                f16x8 a = *(const f16x8*)(hR + rowA * 512 + kt * 32 + quad * 8);
                ah0 = mfma16(a, __builtin_bit_cast(f16x8, ldsB[(0 * 16 + kt) * 64 + lane]), ah0);
                ah1 = mfma16(a, __builtin_bit_cast(f16x8, ldsB[(1 * 16 + kt) * 64 + lane]), ah1);
                ah2 = mfma16(a, __builtin_bit_cast(f16x8, ldsB[(2 * 16 + kt) * 64 + lane]), ah2);
            }
#pragma unroll
            for (int i = 0; i < 4; ++i) {
                const int b  = rowC + i;
                const int cu = cslice + l16;
                float r = sigm_f(ax0[i] + bi_r + ah0[i]);
                float z = sigm_f(ax1[i] + bi_z + ah1[i]);
                float n = tanh_f(ax2[i] + bi_n + r * (ah2[i] + bhn));
                float hnew = (1.0f - z) * n + z * hstate[i];
                hstate[i] = hnew;
                hW[b * 512 + cu] = (_Float16)hnew;
                yW[b * 512 + cu] = (_Float16)tanh_f(hnew);
                if (s == T_STEPS - 1) c0_out[b * 512 + cu] = hnew;
            }
        }

        if (isL1 && s >= 1) {
            const _Float16* hR = h1buf + pr * 32768;
            _Float16* hW = h1buf + (pr ^ 1) * 32768;
            const _Float16* yR = y0buf + pr * 32768;  // y0 from global step s-1

            f32x4 ah0 = {0,0,0,0}, ah1 = {0,0,0,0}, ah2 = {0,0,0,0};
            f32x4 ax0 = {0,0,0,0}, ax1 = {0,0,0,0}, ax2 = {0,0,0,0};

#pragma unroll
            for (int kt = 0; kt < 16; ++kt) {
                f16x8 ah = *(const f16x8*)(hR + rowA * 512 + kt * 32 + quad * 8);
                f16x8 ay = *(const f16x8*)(yR + rowA * 512 + kt * 32 + quad * 8);
                ah0 = mfma16(ah, __builtin_bit_cast(f16x8, ldsB[(0 * 16 + kt) * 64 + lane]), ah0);
                ah1 = mfma16(ah, __builtin_bit_cast(f16x8, ldsB[(1 * 16 + kt) * 64 + lane]), ah1);
                ah2 = mfma16(ah, __builtin_bit_cast(f16x8, ldsB[(2 * 16 + kt) * 64 + lane]), ah2);
                ax0 = mfma16(ay, wif[0 * 16 + kt], ax0);
                ax1 = mfma16(ay, wif[1 * 16 + kt], ax1);
                ax2 = mfma16(ay, wif[2 * 16 + kt], ax2);
            }
#pragma unroll
            for (int i = 0; i < 4; ++i) {
                const int b  = rowC + i;
                const int cu = cslice + l16;
                float r = sigm_f(ax0[i] + bi_r + ah0[i]);
                float z = sigm_f(ax1[i] + bi_z + ah1[i]);
                float n = tanh_f(ax2[i] + bi_n + r * (ah2[i] + bhn));
                float hnew = (1.0f - z) * n + z * hstate[i];
                hstate[i] = hnew;
                hW[b * 512 + cu] = (_Float16)hnew;
                if (s == T_STEPS) c1_out[b * 512 + cu] = hnew;
            }
        }

        if (s < T_STEPS) bar_arrive(flags, wg, (unsigned)(s + 1));
    }
}

// out = tanh(tanh(c1) @ W_out + b_out) : [64,512] @ [512,512], fp32
__global__ __launch_bounds__(256) void dense_out(
    const float* __restrict__ c1, const float* __restrict__ Wout,
    const float* __restrict__ bout, float* __restrict__ out)
{
    __shared__ float a[512];
    const int b = blockIdx.x, tid = threadIdx.x;
    a[tid]       = tanh_f(c1[b * 512 + tid]);
    a[tid + 256] = tanh_f(c1[b * 512 + tid + 256]);
    __syncthreads();
    float acc0 = 0.f, acc1 = 0.f;
#pragma unroll 4
    for (int k = 0; k < 512; ++k) {
        const float av = a[k];
        acc0 += av * Wout[k * 512 + tid];
        acc1 += av * Wout[k * 512 + tid + 256];
    }
    out[b * 512 + tid]       = tanh_f(acc0 + bout[tid]);
    out[b * 512 + tid + 256] = tanh_f(acc1 + bout[tid + 256]);
}

extern "C" void kernel_launch(void* const* d_in, const int* in_sizes, int n_in,
                              void* d_out, int out_size, void* d_ws, size_t ws_size,
                              hipStream_t stream)
{
    const float* x    = (const float*)d_in[0];
    const float* Wi0  = (const float*)d_in[1];
    const float* bi0  = (const float*)d_in[2];
    const float* Wh0  = (const float*)d_in[3];
    const float* bhn0 = (const float*)d_in[4];
    const float* Wi1  = (const float*)d_in[5];
    const float* bi1  = (const float*)d_in[6];
    const float* Wh1  = (const float*)d_in[7];
    const float* bhn1 = (const float*)d_in[8];
    const float* Wout = (const float*)d_in[9];
    const float* bout = (const float*)d_in[10];
    float* out = (float*)d_out;
    unsigned char* ws = (unsigned char*)d_ws;

    // zero h/y double buffers' first slots + flag array (ws poisoned 0xAA)
    hipMemsetAsync(ws, 0, FLAG_OFF + 8192, stream);

    gru_scan<<<NWG_TOT, 256, 0, stream>>>(x, Wi0, bi0, Wh0, bhn0,
                                          Wi1, bi1, Wh1, bhn1,
                                          out + 32768, out + 65536, ws);
    dense_out<<<64, 256, 0, stream>>>(out + 65536, Wout, bout, out);
}

// Round 3
// 9350.471 us; speedup vs baseline: 1.2263x; 1.0949x over previous
//
#include <hip/hip_runtime.h>

// ---------------------------------------------------------------------------
// 2-layer GRU (B=64, T=1024, D=256, H=512) + dense head, persistent-RNN style.
// Layer1 trails layer0 by 1 step; W_h in LDS, W_i in registers, fp16 MFMA
// (fp32 accum), fp32 carried state. Cross-wg exchange uses FENCE-FREE
// device-coherent accesses: all h/y loads+stores and barrier flags are
// relaxed agent-scope atomics (sc1 path, straight to MALL) so no
// buffer_wbl2/buffer_inv L2 maintenance is ever emitted. Ordering:
// producer vmcnt(0)+__syncthreads before flag store; consumer loads are
// control-dependent on poll success.
// ---------------------------------------------------------------------------

#define T_STEPS 1024
#define NWG_L0  32
#define NWG_L1  32
#define NWG_TOT 64

typedef _Float16 f16x8 __attribute__((ext_vector_type(8)));
typedef float    f32x4 __attribute__((ext_vector_type(4)));

// ws layout (bytes):
//   0      h0[2][64][512] f16   (131072)
//   131072 h1[2][64][512] f16   (131072)
//   262144 y0[2][64][512] f16   (131072)
//   393216 flags[64] (128B stride)  (8192)
#define H0_OFF   0
#define H1_OFF   131072
#define Y0_OFF   262144
#define FLAG_OFF 393216
#define FLAG_STRIDE 32   // uints = 128 B

__device__ __forceinline__ float sigm_f(float x)  { return 1.0f / (1.0f + __expf(-x)); }
__device__ __forceinline__ float tanh_f(float x)  { return 2.0f / (1.0f + __expf(-2.0f * x)) - 1.0f; }

__device__ __forceinline__ f32x4 mfma16(f16x8 a, f16x8 b, f32x4 c) {
    return __builtin_amdgcn_mfma_f32_16x16x32_f16(a, b, c, 0, 0, 0);
}

__device__ __forceinline__ f16x8 pack8(const float* __restrict__ src, int stride) {
    f16x8 r;
#pragma unroll
    for (int j = 0; j < 8; ++j) r[j] = (_Float16)src[j * stride];
    return r;
}

// device-coherent (sc1) 16B fragment load as 2x8B relaxed agent atomics
__device__ __forceinline__ f16x8 ld_frag_dev(const _Float16* p) {
    union { unsigned long long u[2]; f16x8 f; } cvt;
    cvt.u[0] = __hip_atomic_load((const unsigned long long*)p,
                                 __ATOMIC_RELAXED, __HIP_MEMORY_SCOPE_AGENT);
    cvt.u[1] = __hip_atomic_load((const unsigned long long*)(p + 4),
                                 __ATOMIC_RELAXED, __HIP_MEMORY_SCOPE_AGENT);
    return cvt.f;
}

// device-coherent (sc1) f16 store
__device__ __forceinline__ void st_dev_f16(_Float16* p, float v) {
    unsigned short b = __builtin_bit_cast(unsigned short, (_Float16)v);
    __hip_atomic_store((unsigned short*)p, b, __ATOMIC_RELAXED, __HIP_MEMORY_SCOPE_AGENT);
}

// arrive: drain this wave's stores to the coherence point, wg-sync, set flag.
__device__ __forceinline__ void bar_arrive(unsigned* flags, int wg, unsigned epoch) {
    asm volatile("s_waitcnt vmcnt(0)" ::: "memory");
    __syncthreads();
    if (threadIdx.x == 0)
        __hip_atomic_store(&flags[wg * FLAG_STRIDE], epoch,
                           __ATOMIC_RELAXED, __HIP_MEMORY_SCOPE_AGENT);
}
// wait: wave0 polls all 64 flags (lane i -> flag i); no cache maintenance.
__device__ __forceinline__ void bar_wait(const unsigned* flags, unsigned epoch,
                                         int wave, int lane) {
    if (wave == 0) {
        const unsigned* p = &flags[lane * FLAG_STRIDE];
        for (;;) {
            unsigned v = __hip_atomic_load(p, __ATOMIC_RELAXED, __HIP_MEMORY_SCOPE_AGENT);
            if (__all(v >= epoch)) break;
        }
    }
    __syncthreads();
    asm volatile("" ::: "memory");
}

__global__ __launch_bounds__(256, 1) void gru_scan(
    const float* __restrict__ x,     // [64,1024,256]
    const float* __restrict__ Wi0,   // [256,1536]
    const float* __restrict__ bi0,   // [1536]
    const float* __restrict__ Wh0,   // [512,1536]
    const float* __restrict__ bhn0,  // [512]
    const float* __restrict__ Wi1,   // [512,1536]
    const float* __restrict__ bi1,   // [1536]
    const float* __restrict__ Wh1,   // [512,1536]
    const float* __restrict__ bhn1,  // [512]
    float* __restrict__ c0_out,      // [64,512]
    float* __restrict__ c1_out,      // [64,512]
    unsigned char* __restrict__ ws)
{
    __shared__ uint4 ldsB[48 * 64];  // 48 KB: W_h fragments, frag idx nt*16+kt

    const int tid  = threadIdx.x;
    const int wave = tid >> 6;
    const int lane = tid & 63;
    const int quad = lane >> 4;
    const int l16  = lane & 15;
    const int wg   = blockIdx.x;
    const bool isL1 = (wg >= NWG_L0);
    const int cslice = (isL1 ? (wg - NWG_L0) : wg) * 16;

    _Float16* h0buf = (_Float16*)(ws + H0_OFF);
    _Float16* h1buf = (_Float16*)(ws + H1_OFF);
    _Float16* y0buf = (_Float16*)(ws + Y0_OFF);
    unsigned* flags = (unsigned*)(ws + FLAG_OFF);

    const float* Wh = isL1 ? Wh1 : Wh0;
    const float* Wi = isL1 ? Wi1 : Wi0;

    // ---- stage W_h fragments into LDS ----
    // B-frag (16x16x32): lane holds B[k = kt*32 + quad*8 + j][n = l16]
    for (int f = wave * 12; f < wave * 12 + 12; ++f) {
        int nt = f >> 4, kt = f & 15;
        const float* src = Wh + (kt * 32 + quad * 8) * 1536 + nt * 512 + cslice + l16;
        ldsB[f * 64 + lane] = __builtin_bit_cast(uint4, pack8(src, 1536));
    }

    // ---- W_i fragments in registers ----
    f16x8 wif[48];
    if (!isL1) {
#pragma unroll
        for (int nt = 0; nt < 3; ++nt)
#pragma unroll
            for (int kt = 0; kt < 8; ++kt)
                wif[nt * 8 + kt] = pack8(Wi + (kt * 32 + quad * 8) * 1536 + nt * 512 + cslice + l16, 1536);
    } else {
#pragma unroll
        for (int nt = 0; nt < 3; ++nt)
#pragma unroll
            for (int kt = 0; kt < 16; ++kt)
                wif[nt * 16 + kt] = pack8(Wi + (kt * 32 + quad * 8) * 1536 + nt * 512 + cslice + l16, 1536);
    }

    const float* bi = isL1 ? bi1 : bi0;
    const float* bh = isL1 ? bhn1 : bhn0;
    const float bi_r = bi[cslice + l16];
    const float bi_z = bi[512 + cslice + l16];
    const float bi_n = bi[1024 + cslice + l16];
    const float bhn  = bh[cslice + l16];

    __syncthreads();

    float hstate[4] = {0.f, 0.f, 0.f, 0.f};
    const int rowA = wave * 16 + l16;
    const int rowC = wave * 16 + quad * 4;

    for (int s = 0; s < T_STEPS + 1; ++s) {
        const int pr = s & 1;

        // --- prefetch x for this step (barrier-independent, normal cached) ---
        f32x4 xr[16];
        if (!isL1 && s < T_STEPS) {
            const float* px = x + (size_t)rowA * 262144 + s * 256 + quad * 8;
#pragma unroll
            for (int kt = 0; kt < 8; ++kt) {
                xr[kt * 2]     = *(const f32x4*)(px + kt * 32);
                xr[kt * 2 + 1] = *(const f32x4*)(px + kt * 32 + 4);
            }
        }

        if (s > 0) bar_wait(flags, (unsigned)s, wave, lane);

        if (!isL1 && s < T_STEPS) {
            const _Float16* hR = h0buf + pr * 32768;
            _Float16* hW = h0buf + (pr ^ 1) * 32768;
            _Float16* yW = y0buf + (pr ^ 1) * 32768;

            f32x4 ah0 = {0,0,0,0}, ah1 = {0,0,0,0}, ah2 = {0,0,0,0};
            f32x4 ax0 = {0,0,0,0}, ax1 = {0,0,0,0}, ax2 = {0,0,0,0};

            // input-side: xg = x_t @ W_i0 (K = 256), from prefetched regs
#pragma unroll
            for (int kt = 0; kt < 8; ++kt) {
                f32x4 x0 = xr[kt * 2], x1 = xr[kt * 2 + 1];
                f16x8 a;
                a[0] = (_Float16)x0[0]; a[1] = (_Float16)x0[1]; a[2] = (_Float16)x0[2]; a[3] = (_Float16)x0[3];
                a[4] = (_Float16)x1[0]; a[5] = (_Float16)x1[1]; a[6] = (_Float16)x1[2]; a[7] = (_Float16)x1[3];
                ax0 = mfma16(a, wif[0 * 8 + kt], ax0);
                ax1 = mfma16(a, wif[1 * 8 + kt], ax1);
                ax2 = mfma16(a, wif[2 * 8 + kt], ax2);
            }
            // hidden-side: hg = h @ W_h (K = 512), device-coherent loads
#pragma unroll
            for (int kt = 0; kt < 16; ++kt) {
                f16x8 a = ld_frag_dev(hR + rowA * 512 + kt * 32 + quad * 8);
                ah0 = mfma16(a, __builtin_bit_cast(f16x8, ldsB[(0 * 16 + kt) * 64 + lane]), ah0);
                ah1 = mfma16(a, __builtin_bit_cast(f16x8, ldsB[(1 * 16 + kt) * 64 + lane]), ah1);
                ah2 = mfma16(a, __builtin_bit_cast(f16x8, ldsB[(2 * 16 + kt) * 64 + lane]), ah2);
            }
#pragma unroll
            for (int i = 0; i < 4; ++i) {
                const int b  = rowC + i;
                const int cu = cslice + l16;
                float r = sigm_f(ax0[i] + bi_r + ah0[i]);
                float z = sigm_f(ax1[i] + bi_z + ah1[i]);
                float n = tanh_f(ax2[i] + bi_n + r * (ah2[i] + bhn));
                float hnew = (1.0f - z) * n + z * hstate[i];
                hstate[i] = hnew;
                st_dev_f16(&hW[b * 512 + cu], hnew);
                st_dev_f16(&yW[b * 512 + cu], tanh_f(hnew));
                if (s == T_STEPS - 1) c0_out[b * 512 + cu] = hnew;
            }
        }

        if (isL1 && s >= 1) {
            const _Float16* hR = h1buf + pr * 32768;
            _Float16* hW = h1buf + (pr ^ 1) * 32768;
            const _Float16* yR = y0buf + pr * 32768;  // y0 from global step s-1

            f32x4 ah0 = {0,0,0,0}, ah1 = {0,0,0,0}, ah2 = {0,0,0,0};
            f32x4 ax0 = {0,0,0,0}, ax1 = {0,0,0,0}, ax2 = {0,0,0,0};

#pragma unroll
            for (int kt = 0; kt < 16; ++kt) {
                f16x8 ah = ld_frag_dev(hR + rowA * 512 + kt * 32 + quad * 8);
                f16x8 ay = ld_frag_dev(yR + rowA * 512 + kt * 32 + quad * 8);
                ah0 = mfma16(ah, __builtin_bit_cast(f16x8, ldsB[(0 * 16 + kt) * 64 + lane]), ah0);
                ah1 = mfma16(ah, __builtin_bit_cast(f16x8, ldsB[(1 * 16 + kt) * 64 + lane]), ah1);
                ah2 = mfma16(ah, __builtin_bit_cast(f16x8, ldsB[(2 * 16 + kt) * 64 + lane]), ah2);
                ax0 = mfma16(ay, wif[0 * 16 + kt], ax0);
                ax1 = mfma16(ay, wif[1 * 16 + kt], ax1);
                ax2 = mfma16(ay, wif[2 * 16 + kt], ax2);
            }
#pragma unroll
            for (int i = 0; i < 4; ++i) {
                const int b  = rowC + i;
                const int cu = cslice + l16;
                float r = sigm_f(ax0[i] + bi_r + ah0[i]);
                float z = sigm_f(ax1[i] + bi_z + ah1[i]);
                float n = tanh_f(ax2[i] + bi_n + r * (ah2[i] + bhn));
                float hnew = (1.0f - z) * n + z * hstate[i];
                hstate[i] = hnew;
                st_dev_f16(&hW[b * 512 + cu], hnew);
                if (s == T_STEPS) c1_out[b * 512 + cu] = hnew;
            }
        }

        if (s < T_STEPS) bar_arrive(flags, wg, (unsigned)(s + 1));
    }
}

// out = tanh(tanh(c1) @ W_out + b_out) : [64,512] @ [512,512], fp32
__global__ __launch_bounds__(256) void dense_out(
    const float* __restrict__ c1, const float* __restrict__ Wout,
    const float* __restrict__ bout, float* __restrict__ out)
{
    __shared__ float a[512];
    const int b = blockIdx.x, tid = threadIdx.x;
    a[tid]       = tanh_f(c1[b * 512 + tid]);
    a[tid + 256] = tanh_f(c1[b * 512 + tid + 256]);
    __syncthreads();
    float acc0 = 0.f, acc1 = 0.f;
#pragma unroll 4
    for (int k = 0; k < 512; ++k) {
        const float av = a[k];
        acc0 += av * Wout[k * 512 + tid];
        acc1 += av * Wout[k * 512 + tid + 256];
    }
    out[b * 512 + tid]       = tanh_f(acc0 + bout[tid]);
    out[b * 512 + tid + 256] = tanh_f(acc1 + bout[tid + 256]);
}

extern "C" void kernel_launch(void* const* d_in, const int* in_sizes, int n_in,
                              void* d_out, int out_size, void* d_ws, size_t ws_size,
                              hipStream_t stream)
{
    const float* x    = (const float*)d_in[0];
    const float* Wi0  = (const float*)d_in[1];
    const float* bi0  = (const float*)d_in[2];
    const float* Wh0  = (const float*)d_in[3];
    const float* bhn0 = (const float*)d_in[4];
    const float* Wi1  = (const float*)d_in[5];
    const float* bi1  = (const float*)d_in[6];
    const float* Wh1  = (const float*)d_in[7];
    const float* bhn1 = (const float*)d_in[8];
    const float* Wout = (const float*)d_in[9];
    const float* bout = (const float*)d_in[10];
    float* out = (float*)d_out;
    unsigned char* ws = (unsigned char*)d_ws;

    // zero h/y double buffers + flag array (ws poisoned 0xAA each launch)
    hipMemsetAsync(ws, 0, FLAG_OFF + 8192, stream);

    gru_scan<<<NWG_TOT, 256, 0, stream>>>(x, Wi0, bi0, Wh0, bhn0,
                                          Wi1, bi1, Wh1, bhn1,
                                          out + 32768, out + 65536, ws);
    dense_out<<<64, 256, 0, stream>>>(out + 65536, Wout, bout, out);
}